// Round 1
// baseline (1286.093 us; speedup 1.0000x reference)
//
#include <hip/hip_runtime.h>
#include <math.h>

// Problem constants
#define BB 4
#define SS 64
#define NN 256
#define FF 32
#define HH 64
#define MM (BB*SS)      // 256 graphs
#define NSEQ (BB*NN)    // 1024 sequences
#define TT SS           // 64 timesteps
#define G4 (4*HH)       // 256 gates

__device__ __forceinline__ float sigmoid_f(float x) { return 1.0f / (1.0f + __expf(-x)); }
__device__ __forceinline__ float tanh_f(float x) {
    float t = __expf(-2.0f * fabsf(x));
    float r = (1.0f - t) / (1.0f + t);
    return copysignf(r, x);
}
__device__ __forceinline__ float wave_sum(float v) {
#pragma unroll
    for (int off = 32; off; off >>= 1) v += __shfl_xor(v, off);
    return v;
}
__device__ __forceinline__ float wave_max(float v) {
#pragma unroll
    for (int off = 32; off; off >>= 1) v = fmaxf(v, __shfl_xor(v, off));
    return v;
}

// ---------------------------------------------------------------------------
// GAT layer: one block per graph (256 blocks, 256 threads).
// LDS: h[256][64] (64KB) + attq[4 waves][256 j][4 rows] (16KB) + s1,s2 (2KB)
// ---------------------------------------------------------------------------
template<int FIN>
__global__ __launch_bounds__(256) void gat_kernel(
    const float* __restrict__ xin,   // [M][N][FIN]
    const float* __restrict__ adj,   // [M][N][N]
    const float* __restrict__ W,     // [FIN][64]
    const float* __restrict__ a,     // [128]
    const float* __restrict__ gamma_, const float* __restrict__ beta_,
    float* __restrict__ gout)        // [M][N][64]
{
    __shared__ __align__(16) float h_lds[256 * 64];
    __shared__ __align__(16) float attq[4 * 256 * 4];   // [wave][j][r]
    __shared__ float s1[256], s2[256];

    const int m = blockIdx.x;
    const int t = threadIdx.x;
    const int c = t & 63;      // output column (H)
    const int w = t >> 6;      // wave id

    // W column into registers
    float wreg[FIN];
#pragma unroll
    for (int f = 0; f < FIN; ++f) wreg[f] = W[f * 64 + c];

    // phase 1: h = x @ W  (thread (w,c) covers rows i with i%4==w)
    const float* xg_ = xin + (size_t)m * NN * FIN;
    for (int i0 = 0; i0 < 64; ++i0) {
        int i = (i0 << 2) | w;
        float acc = 0.0f;
#pragma unroll
        for (int f4 = 0; f4 < FIN / 4; ++f4) {
            float4 xv = *(const float4*)&xg_[i * FIN + f4 * 4];
            acc += xv.x * wreg[f4*4] + xv.y * wreg[f4*4+1]
                 + xv.z * wreg[f4*4+2] + xv.w * wreg[f4*4+3];
        }
        h_lds[i * 64 + c] = acc;
    }
    __syncthreads();

    // phase 2: s1 = h@a1, s2 = h@a2 (wave w handles rows [64w, 64w+64))
    const float a1 = a[c], a2 = a[64 + c];
    for (int k = 0; k < 64; ++k) {
        int i = w * 64 + k;
        float hv = h_lds[i * 64 + c];
        float v1 = wave_sum(hv * a1);
        float v2 = wave_sum(hv * a2);
        if (c == 0) { s1[i] = v1; s2[i] = v2; }
    }
    __syncthreads();

    // phase 3: attention + aggregation + LN + ELU, 4 rows (one quad) per wave
    const float* adjm = adj + (size_t)m * NN * NN;
    const float gam = gamma_[c], bet = beta_[c];
    for (int qq = 0; qq < 16; ++qq) {
        int q = w + (qq << 2);     // quad 0..63
        int i0 = q * 4;
        // attention for 4 rows
#pragma unroll
        for (int r = 0; r < 4; ++r) {
            int i = i0 + r;
            float si = s1[i];
            float p[4];
            float maxe = -3.4e38f;
#pragma unroll
            for (int jg = 0; jg < 4; ++jg) {
                int j = jg * 64 + c;
                float e = si + s2[j];
                e = (e > 0.0f) ? e : 0.2f * e;
                float ad = adjm[(size_t)i * NN + j];
                e = (ad > 0.0f) ? e : -9e15f;
                p[jg] = e;
                maxe = fmaxf(maxe, e);
            }
            maxe = wave_max(maxe);
            float sum = 0.0f;
#pragma unroll
            for (int jg = 0; jg < 4; ++jg) { p[jg] = __expf(p[jg] - maxe); sum += p[jg]; }
            sum = wave_sum(sum);
            float rinv = 1.0f / sum;
#pragma unroll
            for (int jg = 0; jg < 4; ++jg)
                attq[w * 1024 + (jg * 64 + c) * 4 + r] = p[jg] * rinv;
        }
        __syncthreads();   // attq visible (also isolates reuse across quads)

        // aggregation: lane c accumulates column c for the 4 rows
        float acc0 = 0, acc1 = 0, acc2 = 0, acc3 = 0;
        const float* aq = &attq[w * 1024];
#pragma unroll 8
        for (int j = 0; j < 256; ++j) {
            float hv = h_lds[j * 64 + c];
            float4 av = *(const float4*)&aq[j * 4];
            acc0 += av.x * hv; acc1 += av.y * hv;
            acc2 += av.z * hv; acc3 += av.w * hv;
        }
        // layernorm over H + elu per row
        float accs[4] = {acc0, acc1, acc2, acc3};
#pragma unroll
        for (int r = 0; r < 4; ++r) {
            float v = accs[r];
            float sm = wave_sum(v);
            float sq = wave_sum(v * v);
            float mu = sm * (1.0f / 64.0f);
            float var = sq * (1.0f / 64.0f) - mu * mu;
            float hn = (v - mu) * rsqrtf(var + 1e-5f) * gam + bet;
            float o = (hn > 0.0f) ? hn : (__expf(hn) - 1.0f);
            gout[((size_t)m * NN + i0 + r) * 64 + c] = o;
        }
        __syncthreads();   // protect attq before next quad's writes
    }
}

// ---------------------------------------------------------------------------
// residual + gate*g, reshaped to sequence layout [B*N][T][H]
// ---------------------------------------------------------------------------
__global__ __launch_bounds__(256) void combine_kernel(
    const float* __restrict__ x,      // [B*S*N][32]
    const float* __restrict__ g1,     // [B*S*N][64]
    const float* __restrict__ res_W,  // [32][64]
    const float* __restrict__ res_b,  // [64]
    const float* __restrict__ alpha_p,
    float* __restrict__ seqout)       // [B*N][T][64]
{
    int row = blockIdx.x * 4 + (threadIdx.x >> 6);   // [0, B*S*N)
    int h = threadIdx.x & 63;
    int mg = row >> 8, n = row & 255;
    int b = mg >> 6, s = mg & 63;
    const float* xr = x + (size_t)row * 32;
    float acc = res_b[h];
#pragma unroll
    for (int f4 = 0; f4 < 8; ++f4) {
        float4 xv = *(const float4*)&xr[f4 * 4];
        acc += xv.x * res_W[(f4*4    ) * 64 + h] + xv.y * res_W[(f4*4 + 1) * 64 + h]
             + xv.z * res_W[(f4*4 + 2) * 64 + h] + xv.w * res_W[(f4*4 + 3) * 64 + h];
    }
    float alpha = fminf(fmaxf(alpha_p[0], 0.0f), 1.0f);
    acc += alpha * g1[(size_t)row * 64 + h];
    seqout[(((size_t)(b * NN + n)) * TT + s) * 64 + h] = acc;
}

// ---------------------------------------------------------------------------
// input-gate GEMM: xg[sd][t][k] = bias[k] + sum_d in[seq][t'][d]*Wih[dir][d][k]
// one block per (seq,dir); Wih column in VGPRs; whole input sequence in LDS
// ---------------------------------------------------------------------------
template<int D>
__global__ __launch_bounds__(256) void xg_kernel(
    const float* __restrict__ in,    // [NSEQ][T][D]
    const float* __restrict__ Wih,   // [2][D][256]
    const float* __restrict__ bih,   // [2][256]
    const float* __restrict__ bhh,   // [2][256]
    float* __restrict__ xg)          // [2*NSEQ][T][256]
{
    int sd = blockIdx.x;
    int seq = sd >> 1, dir = sd & 1;
    int k = threadIdx.x;
    float wv[D];
#pragma unroll
    for (int d = 0; d < D; ++d) wv[d] = Wih[((size_t)dir * D + d) * 256 + k];
    float bias = bih[dir * 256 + k] + bhh[dir * 256 + k];

    __shared__ __align__(16) float xin_s[TT * D];
    const float* src = in + (size_t)seq * TT * D;
    for (int idx = threadIdx.x; idx < TT * D / 4; idx += 256)
        ((float4*)xin_s)[idx] = ((const float4*)src)[idx];
    __syncthreads();

    float* dst = xg + (size_t)sd * TT * 256;
    for (int step = 0; step < TT; ++step) {
        int trow = dir ? (TT - 1 - step) : step;
        const float* xr = &xin_s[trow * D];
        float acc = bias;
#pragma unroll
        for (int d4 = 0; d4 < D / 4; ++d4) {
            float4 xv = *(const float4*)&xr[d4 * 4];
            acc += xv.x * wv[d4*4] + xv.y * wv[d4*4+1]
                 + xv.z * wv[d4*4+2] + xv.w * wv[d4*4+3];
        }
        dst[step * 256 + k] = acc;
    }
}

// ---------------------------------------------------------------------------
// LSTM recurrence: one block per (seq,dir); thread = gate k; Whh col in VGPRs
// ---------------------------------------------------------------------------
__global__ __launch_bounds__(256) void lstm_rec_kernel(
    const float* __restrict__ xg,    // [2*NSEQ][T][256] (scan order)
    const float* __restrict__ Whh,   // [2][64][256]
    float* __restrict__ out,         // write_all: o1 [NSEQ][T][128]; else final [NSEQ][128]
    int write_all)
{
    int sd = blockIdx.x;
    int seq = sd >> 1, dir = sd & 1;
    int t = threadIdx.x;
    float whh[64];
#pragma unroll
    for (int j = 0; j < 64; ++j) whh[j] = Whh[((size_t)dir * 64 + j) * 256 + t];

    __shared__ __align__(16) float h_s[64];
    __shared__ float gbuf[256];
    if (t < 64) h_s[t] = 0.0f;
    float cst = 0.0f;
    const float* xgb = xg + (size_t)sd * TT * 256;
    __syncthreads();

    for (int step = 0; step < TT; ++step) {
        float g = xgb[step * 256 + t];
#pragma unroll
        for (int j4 = 0; j4 < 16; ++j4) {
            float4 hv = *(const float4*)&h_s[j4 * 4];
            g += hv.x * whh[j4*4] + hv.y * whh[j4*4+1]
               + hv.z * whh[j4*4+2] + hv.w * whh[j4*4+3];
        }
        float act = (t < 128 || t >= 192) ? sigmoid_f(g) : tanh_f(g);
        gbuf[t] = act;
        __syncthreads();
        if (t < 64) {
            float iv = gbuf[t], fv = gbuf[64 + t], gv = gbuf[128 + t], ov = gbuf[192 + t];
            cst = fv * cst + iv * gv;
            float h = ov * tanh_f(cst);
            h_s[t] = h;
            if (write_all) {
                int t_out = dir ? (TT - 1 - step) : step;
                out[((size_t)seq * TT + t_out) * 128 + dir * 64 + t] = h;
            } else if (step == TT - 1) {
                out[(size_t)seq * 128 + dir * 64 + t] = h;
            }
        }
        __syncthreads();
    }
}

// ---------------------------------------------------------------------------
// final FC: pred[seq] = final[seq] . fc_W + fc_b
// ---------------------------------------------------------------------------
__global__ __launch_bounds__(256) void fc_kernel(
    const float* __restrict__ fin,   // [NSEQ][128]
    const float* __restrict__ fc_W,  // [128]
    const float* __restrict__ fc_b,  // [1]
    float* __restrict__ outp)        // [NSEQ]
{
    int s = blockIdx.x * 256 + threadIdx.x;
    const float* fr = fin + (size_t)s * 128;
    float acc = fc_b[0];
#pragma unroll
    for (int k4 = 0; k4 < 32; ++k4) {
        float4 fv = *(const float4*)&fr[k4 * 4];
        float4 wv2 = *(const float4*)&fc_W[k4 * 4];
        acc += fv.x * wv2.x + fv.y * wv2.y + fv.z * wv2.z + fv.w * wv2.w;
    }
    outp[s] = acc;
}

// ---------------------------------------------------------------------------
extern "C" void kernel_launch(void* const* d_in, const int* in_sizes, int n_in,
                              void* d_out, int out_size, void* d_ws, size_t ws_size,
                              hipStream_t stream) {
    const float* x       = (const float*)d_in[0];
    const float* adj     = (const float*)d_in[1];
    const float* gat0_W  = (const float*)d_in[2];
    const float* gat0_a  = (const float*)d_in[3];
    const float* gat0_g  = (const float*)d_in[4];
    const float* gat0_b  = (const float*)d_in[5];
    const float* gat1_W  = (const float*)d_in[6];
    const float* gat1_a  = (const float*)d_in[7];
    const float* gat1_g  = (const float*)d_in[8];
    const float* gat1_b  = (const float*)d_in[9];
    const float* res_W   = (const float*)d_in[10];
    const float* res_b   = (const float*)d_in[11];
    const float* alpha_g = (const float*)d_in[12];
    const float* l0_Wih  = (const float*)d_in[13];
    const float* l0_Whh  = (const float*)d_in[14];
    const float* l0_bih  = (const float*)d_in[15];
    const float* l0_bhh  = (const float*)d_in[16];
    const float* l1_Wih  = (const float*)d_in[17];
    const float* l1_Whh  = (const float*)d_in[18];
    const float* l1_bih  = (const float*)d_in[19];
    const float* l1_bhh  = (const float*)d_in[20];
    const float* fc_W    = (const float*)d_in[21];
    const float* fc_b    = (const float*)d_in[22];

    float* ws = (float*)d_ws;
    // workspace layout (floats); total 46,268,416 floats = ~185 MB
    float* g0    = ws;                    // 4,194,304   [M][N][64]
    float* g1    = ws + 4194304;          // 4,194,304   [M][N][64]
    float* seq   = ws + 8388608;          // 4,194,304   [B*N][T][64]
    float* xg    = ws + 12582912;         // 33,554,432  [2*NSEQ][T][256]
    float* fin   = ws + 46137344;         // 131,072     [NSEQ][128]
    float* o1    = ws;                    // reuse g0+g1 8,388,608 [NSEQ][T][128]

    gat_kernel<32><<<MM, 256, 0, stream>>>(x, adj, gat0_W, gat0_a, gat0_g, gat0_b, g0);
    gat_kernel<64><<<MM, 256, 0, stream>>>(g0, adj, gat1_W, gat1_a, gat1_g, gat1_b, g1);
    combine_kernel<<<(BB*SS*NN)/4, 256, 0, stream>>>(x, g1, res_W, res_b, alpha_g, seq);
    xg_kernel<64><<<2*NSEQ, 256, 0, stream>>>(seq, l0_Wih, l0_bih, l0_bhh, xg);
    lstm_rec_kernel<<<2*NSEQ, 256, 0, stream>>>(xg, l0_Whh, o1, 1);
    xg_kernel<128><<<2*NSEQ, 256, 0, stream>>>(o1, l1_Wih, l1_bih, l1_bhh, xg);
    lstm_rec_kernel<<<2*NSEQ, 256, 0, stream>>>(xg, l1_Whh, fin, 0);
    fc_kernel<<<NSEQ/256, 256, 0, stream>>>(fin, fc_W, fc_b, (float*)d_out);
}

// Round 2
// 1005.923 us; speedup vs baseline: 1.2785x; 1.2785x over previous
//
#include <hip/hip_runtime.h>
#include <math.h>

// Problem constants
#define BB 4
#define SS 64
#define NN 256
#define FF 32
#define HH 64
#define MM (BB*SS)      // 256 graphs
#define NSEQ (BB*NN)    // 1024 sequences
#define TT SS           // 64 timesteps
#define MROWS (NSEQ*TT) // 65536 GEMM rows

__device__ __forceinline__ float sigmoid_f(float x) { return 1.0f / (1.0f + __expf(-x)); }
__device__ __forceinline__ float tanh_f(float x) {
    float t = __expf(-2.0f * fabsf(x));
    float r = (1.0f - t) / (1.0f + t);
    return copysignf(r, x);
}
__device__ __forceinline__ float wave_sum(float v) {
#pragma unroll
    for (int off = 32; off; off >>= 1) v += __shfl_xor(v, off);
    return v;
}
__device__ __forceinline__ float wave_max(float v) {
#pragma unroll
    for (int off = 32; off; off >>= 1) v = fmaxf(v, __shfl_xor(v, off));
    return v;
}

// ---------------------------------------------------------------------------
// GAT layer: one block per graph (256 blocks, 256 threads).
// LDS: h[256][64] (64KB) + attq[4 waves][256 j][4 rows] (16KB) + s1,s2 (2KB)
// ---------------------------------------------------------------------------
template<int FIN>
__global__ __launch_bounds__(256) void gat_kernel(
    const float* __restrict__ xin,   // [M][N][FIN]
    const float* __restrict__ adj,   // [M][N][N]
    const float* __restrict__ W,     // [FIN][64]
    const float* __restrict__ a,     // [128]
    const float* __restrict__ gamma_, const float* __restrict__ beta_,
    float* __restrict__ gout)        // [M][N][64]
{
    __shared__ __align__(16) float h_lds[256 * 64];
    __shared__ __align__(16) float attq[4 * 256 * 4];   // [wave][j][r] — per-wave private
    __shared__ float s1[256], s2[256];

    const int m = blockIdx.x;
    const int t = threadIdx.x;
    const int c = t & 63;      // output column (H)
    const int w = t >> 6;      // wave id

    // W column into registers
    float wreg[FIN];
#pragma unroll
    for (int f = 0; f < FIN; ++f) wreg[f] = W[f * 64 + c];

    // phase 1: h = x @ W  (thread (w,c) covers rows i with i%4==w)
    const float* xg_ = xin + (size_t)m * NN * FIN;
    for (int i0 = 0; i0 < 64; ++i0) {
        int i = (i0 << 2) | w;
        float acc = 0.0f;
#pragma unroll
        for (int f4 = 0; f4 < FIN / 4; ++f4) {
            float4 xv = *(const float4*)&xg_[i * FIN + f4 * 4];
            acc += xv.x * wreg[f4*4] + xv.y * wreg[f4*4+1]
                 + xv.z * wreg[f4*4+2] + xv.w * wreg[f4*4+3];
        }
        h_lds[i * 64 + c] = acc;
    }
    __syncthreads();

    // phase 2: s1 = h@a1, s2 = h@a2 (wave w handles rows [64w, 64w+64))
    const float a1 = a[c], a2 = a[64 + c];
    for (int k = 0; k < 64; ++k) {
        int i = w * 64 + k;
        float hv = h_lds[i * 64 + c];
        float v1 = wave_sum(hv * a1);
        float v2 = wave_sum(hv * a2);
        if (c == 0) { s1[i] = v1; s2[i] = v2; }
    }
    __syncthreads();

    // phase 3: attention + aggregation + LN + ELU, 4 rows (one quad) per wave.
    // attq slice is per-wave private: NO block barriers needed in this loop —
    // intra-wave LDS RAW/WAR ordering is guaranteed by in-order DS + lgkmcnt.
    const float* adjm = adj + (size_t)m * NN * NN;
    const float gam = gamma_[c], bet = beta_[c];
    for (int qq = 0; qq < 16; ++qq) {
        int q = w + (qq << 2);     // quad 0..63
        int i0 = q * 4;
        // attention for 4 rows
#pragma unroll
        for (int r = 0; r < 4; ++r) {
            int i = i0 + r;
            float si = s1[i];
            float p[4];
            float maxe = -3.4e38f;
#pragma unroll
            for (int jg = 0; jg < 4; ++jg) {
                int j = jg * 64 + c;
                float e = si + s2[j];
                e = (e > 0.0f) ? e : 0.2f * e;
                float ad = adjm[(size_t)i * NN + j];
                e = (ad > 0.0f) ? e : -9e15f;
                p[jg] = e;
                maxe = fmaxf(maxe, e);
            }
            maxe = wave_max(maxe);
            float sum = 0.0f;
#pragma unroll
            for (int jg = 0; jg < 4; ++jg) { p[jg] = __expf(p[jg] - maxe); sum += p[jg]; }
            sum = wave_sum(sum);
            float rinv = 1.0f / sum;
#pragma unroll
            for (int jg = 0; jg < 4; ++jg)
                attq[w * 1024 + (jg * 64 + c) * 4 + r] = p[jg] * rinv;
        }

        // aggregation: lane c accumulates column c for the 4 rows
        float acc0 = 0, acc1 = 0, acc2 = 0, acc3 = 0;
        const float* aq = &attq[w * 1024];
#pragma unroll 8
        for (int j = 0; j < 256; ++j) {
            float hv = h_lds[j * 64 + c];
            float4 av = *(const float4*)&aq[j * 4];
            acc0 += av.x * hv; acc1 += av.y * hv;
            acc2 += av.z * hv; acc3 += av.w * hv;
        }
        // layernorm over H + elu per row
        float accs[4] = {acc0, acc1, acc2, acc3};
#pragma unroll
        for (int r = 0; r < 4; ++r) {
            float v = accs[r];
            float sm = wave_sum(v);
            float sq = wave_sum(v * v);
            float mu = sm * (1.0f / 64.0f);
            float var = sq * (1.0f / 64.0f) - mu * mu;
            float hn = (v - mu) * rsqrtf(var + 1e-5f) * gam + bet;
            float o = (hn > 0.0f) ? hn : (__expf(hn) - 1.0f);
            gout[((size_t)m * NN + i0 + r) * 64 + c] = o;
        }
    }
}

// ---------------------------------------------------------------------------
// residual + gate*g, reshaped to sequence layout [B*N][T][H]
// ---------------------------------------------------------------------------
__global__ __launch_bounds__(256) void combine_kernel(
    const float* __restrict__ x,      // [B*S*N][32]
    const float* __restrict__ g1,     // [B*S*N][64]
    const float* __restrict__ res_W,  // [32][64]
    const float* __restrict__ res_b,  // [64]
    const float* __restrict__ alpha_p,
    float* __restrict__ seqout)       // [B*N][T][64]
{
    int row = blockIdx.x * 4 + (threadIdx.x >> 6);   // [0, B*S*N)
    int h = threadIdx.x & 63;
    int mg = row >> 8, n = row & 255;
    int b = mg >> 6, s = mg & 63;
    const float* xr = x + (size_t)row * 32;
    float acc = res_b[h];
#pragma unroll
    for (int f4 = 0; f4 < 8; ++f4) {
        float4 xv = *(const float4*)&xr[f4 * 4];
        acc += xv.x * res_W[(f4*4    ) * 64 + h] + xv.y * res_W[(f4*4 + 1) * 64 + h]
             + xv.z * res_W[(f4*4 + 2) * 64 + h] + xv.w * res_W[(f4*4 + 3) * 64 + h];
    }
    float alpha = fminf(fmaxf(alpha_p[0], 0.0f), 1.0f);
    acc += alpha * g1[(size_t)row * 64 + h];
    seqout[(((size_t)(b * NN + n)) * TT + s) * 64 + h] = acc;
}

// ---------------------------------------------------------------------------
// xg GEMM: C[65536 x 256] = A[65536 x K] @ Wih[dir][K x 256] + bias, per dir.
// Natural t order (no reversal — the LSTM reads reversed for dir=1).
// Block tile 64 rows x 128 cols, thread tile 8x4, K-chunks of 32 in LDS.
// grid: (MROWS/64, 2, 2)  [row tile, col half, dir]
// ---------------------------------------------------------------------------
template<int K>
__global__ __launch_bounds__(256) void xg_gemm_kernel(
    const float* __restrict__ A,     // [65536][K]
    const float* __restrict__ Wih,   // [2][K][256]
    const float* __restrict__ bih,   // [2][256]
    const float* __restrict__ bhh,   // [2][256]
    float* __restrict__ xg)          // [2][65536][256]
{
    constexpr int KC = 32;
    __shared__ __align__(16) float a_s[64 * KC];    // 8 KB
    __shared__ __align__(16) float b_s[KC * 128];   // 16 KB

    const int tid = threadIdx.x;
    const int m0  = blockIdx.x * 64;
    const int c0  = blockIdx.y * 128;
    const int dir = blockIdx.z;

    const int tx = tid & 31;        // cols: c0 + tx*4 .. +3
    const int ty = tid >> 5;        // rows: m0 + ty*8 .. +7

    float acc[8][4];
#pragma unroll
    for (int r = 0; r < 8; ++r)
#pragma unroll
        for (int c = 0; c < 4; ++c) acc[r][c] = 0.0f;

    const float* Bd = Wih + (size_t)dir * K * 256;

    for (int kc = 0; kc < K; kc += KC) {
        // stage A tile: 64 rows x 32 k  (512 float4, 2/thread)
        {
            int idx = tid;
#pragma unroll
            for (int i = 0; i < 2; ++i, idx += 256) {
                int row = idx >> 3, k4 = (idx & 7) << 2;
                *(float4*)&a_s[row * KC + k4] =
                    *(const float4*)&A[(size_t)(m0 + row) * K + kc + k4];
            }
        }
        // stage B tile: 32 k x 128 cols (1024 float4, 4/thread)
        {
            int idx = tid;
#pragma unroll
            for (int i = 0; i < 4; ++i, idx += 256) {
                int kr = idx >> 5, c4 = (idx & 31) << 2;
                *(float4*)&b_s[kr * 128 + c4] =
                    *(const float4*)&Bd[(size_t)(kc + kr) * 256 + c0 + c4];
            }
        }
        __syncthreads();
#pragma unroll
        for (int kk = 0; kk < KC; kk += 4) {
            float4 bf0 = *(const float4*)&b_s[(kk + 0) * 128 + tx * 4];
            float4 bf1 = *(const float4*)&b_s[(kk + 1) * 128 + tx * 4];
            float4 bf2 = *(const float4*)&b_s[(kk + 2) * 128 + tx * 4];
            float4 bf3 = *(const float4*)&b_s[(kk + 3) * 128 + tx * 4];
#pragma unroll
            for (int r = 0; r < 8; ++r) {
                float4 af = *(const float4*)&a_s[(ty * 8 + r) * KC + kk];
                acc[r][0] += af.x * bf0.x + af.y * bf1.x + af.z * bf2.x + af.w * bf3.x;
                acc[r][1] += af.x * bf0.y + af.y * bf1.y + af.z * bf2.y + af.w * bf3.y;
                acc[r][2] += af.x * bf0.z + af.y * bf1.z + af.z * bf2.z + af.w * bf3.z;
                acc[r][3] += af.x * bf0.w + af.y * bf1.w + af.z * bf2.w + af.w * bf3.w;
            }
        }
        __syncthreads();
    }

    // bias + store
    float4 b1 = *(const float4*)&bih[dir * 256 + c0 + tx * 4];
    float4 b2 = *(const float4*)&bhh[dir * 256 + c0 + tx * 4];
    float4 bias = make_float4(b1.x + b2.x, b1.y + b2.y, b1.z + b2.z, b1.w + b2.w);
    float* out = xg + (size_t)dir * MROWS * 256;
#pragma unroll
    for (int r = 0; r < 8; ++r) {
        float4 v = make_float4(acc[r][0] + bias.x, acc[r][1] + bias.y,
                               acc[r][2] + bias.z, acc[r][3] + bias.w);
        *(float4*)&out[(size_t)(m0 + ty * 8 + r) * 256 + c0 + tx * 4] = v;
    }
}

// ---------------------------------------------------------------------------
// LSTM recurrence: one block per (seq,dir); thread = gate k; Whh col in VGPRs.
// xg is [2][NSEQ][T][256] in NATURAL t order; dir=1 reads reversed.
// ---------------------------------------------------------------------------
__global__ __launch_bounds__(256) void lstm_rec_kernel(
    const float* __restrict__ xg,    // [2][NSEQ][T][256]
    const float* __restrict__ Whh,   // [2][64][256]
    float* __restrict__ out,         // write_all: o1 [NSEQ][T][128]; else final [NSEQ][128]
    int write_all)
{
    int sd = blockIdx.x;
    int seq = sd >> 1, dir = sd & 1;
    int t = threadIdx.x;
    float whh[64];
#pragma unroll
    for (int j = 0; j < 64; ++j) whh[j] = Whh[((size_t)dir * 64 + j) * 256 + t];

    __shared__ __align__(16) float h_s[64];
    __shared__ float gbuf[256];
    if (t < 64) h_s[t] = 0.0f;
    float cst = 0.0f;
    const float* xgb = xg + ((size_t)dir * NSEQ + seq) * TT * 256;
    __syncthreads();

    for (int step = 0; step < TT; ++step) {
        int trow = dir ? (TT - 1 - step) : step;
        float g = xgb[trow * 256 + t];
#pragma unroll
        for (int j4 = 0; j4 < 16; ++j4) {
            float4 hv = *(const float4*)&h_s[j4 * 4];
            g += hv.x * whh[j4*4] + hv.y * whh[j4*4+1]
               + hv.z * whh[j4*4+2] + hv.w * whh[j4*4+3];
        }
        float act = (t < 128 || t >= 192) ? sigmoid_f(g) : tanh_f(g);
        gbuf[t] = act;
        __syncthreads();
        if (t < 64) {
            float iv = gbuf[t], fv = gbuf[64 + t], gv = gbuf[128 + t], ov = gbuf[192 + t];
            cst = fv * cst + iv * gv;
            float h = ov * tanh_f(cst);
            h_s[t] = h;
            if (write_all) {
                int t_out = dir ? (TT - 1 - step) : step;
                out[((size_t)seq * TT + t_out) * 128 + dir * 64 + t] = h;
            } else if (step == TT - 1) {
                out[(size_t)seq * 128 + dir * 64 + t] = h;
            }
        }
        __syncthreads();
    }
}

// ---------------------------------------------------------------------------
// final FC: pred[seq] = final[seq] . fc_W + fc_b
// ---------------------------------------------------------------------------
__global__ __launch_bounds__(256) void fc_kernel(
    const float* __restrict__ fin,   // [NSEQ][128]
    const float* __restrict__ fc_W,  // [128]
    const float* __restrict__ fc_b,  // [1]
    float* __restrict__ outp)        // [NSEQ]
{
    int s = blockIdx.x * 256 + threadIdx.x;
    const float* fr = fin + (size_t)s * 128;
    float acc = fc_b[0];
#pragma unroll
    for (int k4 = 0; k4 < 32; ++k4) {
        float4 fv = *(const float4*)&fr[k4 * 4];
        float4 wv2 = *(const float4*)&fc_W[k4 * 4];
        acc += fv.x * wv2.x + fv.y * wv2.y + fv.z * wv2.z + fv.w * wv2.w;
    }
    outp[s] = acc;
}

// ---------------------------------------------------------------------------
extern "C" void kernel_launch(void* const* d_in, const int* in_sizes, int n_in,
                              void* d_out, int out_size, void* d_ws, size_t ws_size,
                              hipStream_t stream) {
    const float* x       = (const float*)d_in[0];
    const float* adj     = (const float*)d_in[1];
    const float* gat0_W  = (const float*)d_in[2];
    const float* gat0_a  = (const float*)d_in[3];
    const float* gat0_g  = (const float*)d_in[4];
    const float* gat0_b  = (const float*)d_in[5];
    const float* gat1_W  = (const float*)d_in[6];
    const float* gat1_a  = (const float*)d_in[7];
    const float* gat1_g  = (const float*)d_in[8];
    const float* gat1_b  = (const float*)d_in[9];
    const float* res_W   = (const float*)d_in[10];
    const float* res_b   = (const float*)d_in[11];
    const float* alpha_g = (const float*)d_in[12];
    const float* l0_Wih  = (const float*)d_in[13];
    const float* l0_Whh  = (const float*)d_in[14];
    const float* l0_bih  = (const float*)d_in[15];
    const float* l0_bhh  = (const float*)d_in[16];
    const float* l1_Wih  = (const float*)d_in[17];
    const float* l1_Whh  = (const float*)d_in[18];
    const float* l1_bih  = (const float*)d_in[19];
    const float* l1_bhh  = (const float*)d_in[20];
    const float* fc_W    = (const float*)d_in[21];
    const float* fc_b    = (const float*)d_in[22];

    float* ws = (float*)d_ws;
    // workspace layout (floats); total 46,268,416 floats = ~185 MB
    float* g0    = ws;                    // 4,194,304   [M][N][64]
    float* g1    = ws + 4194304;          // 4,194,304   [M][N][64]
    float* seq   = ws + 8388608;          // 4,194,304   [B*N][T][64]
    float* xg    = ws + 12582912;         // 33,554,432  [2][65536][256]
    float* fin   = ws + 46137344;         // 131,072     [NSEQ][128]
    float* o1    = ws;                    // reuse g0+g1 8,388,608 [NSEQ][T][128]

    gat_kernel<32><<<MM, 256, 0, stream>>>(x, adj, gat0_W, gat0_a, gat0_g, gat0_b, g0);
    gat_kernel<64><<<MM, 256, 0, stream>>>(g0, adj, gat1_W, gat1_a, gat1_g, gat1_b, g1);
    combine_kernel<<<(BB*SS*NN)/4, 256, 0, stream>>>(x, g1, res_W, res_b, alpha_g, seq);
    xg_gemm_kernel<64><<<dim3(MROWS/64, 2, 2), 256, 0, stream>>>(seq, l0_Wih, l0_bih, l0_bhh, xg);
    lstm_rec_kernel<<<2*NSEQ, 256, 0, stream>>>(xg, l0_Whh, o1, 1);
    xg_gemm_kernel<128><<<dim3(MROWS/64, 2, 2), 256, 0, stream>>>(o1, l1_Wih, l1_bih, l1_bhh, xg);
    lstm_rec_kernel<<<2*NSEQ, 256, 0, stream>>>(xg, l1_Whh, fin, 0);
    fc_kernel<<<NSEQ/256, 256, 0, stream>>>(fin, fc_W, fc_b, (float*)d_out);
}

// Round 3
// 894.745 us; speedup vs baseline: 1.4374x; 1.1243x over previous
//
#include <hip/hip_runtime.h>
#include <math.h>

// Problem constants
#define BB 4
#define SS 64
#define NN 256
#define FF 32
#define HH 64
#define MM (BB*SS)      // 256 graphs
#define NSEQ (BB*NN)    // 1024 sequences
#define TT SS           // 64 timesteps
#define MROWS (NSEQ*TT) // 65536 GEMM rows

__device__ __forceinline__ float sigmoid_f(float x) { return 1.0f / (1.0f + __expf(-x)); }
__device__ __forceinline__ float tanh_f(float x) {
    float t = __expf(-2.0f * fabsf(x));
    float r = (1.0f - t) / (1.0f + t);
    return copysignf(r, x);
}
__device__ __forceinline__ float wave_sum(float v) {
#pragma unroll
    for (int off = 32; off; off >>= 1) v += __shfl_xor(v, off);
    return v;
}
__device__ __forceinline__ float wave_max(float v) {
#pragma unroll
    for (int off = 32; off; off >>= 1) v = fmaxf(v, __shfl_xor(v, off));
    return v;
}

// ---------------------------------------------------------------------------
// GAT layer: one block per graph (256 blocks, 256 threads).
// ---------------------------------------------------------------------------
template<int FIN>
__global__ __launch_bounds__(256) void gat_kernel(
    const float* __restrict__ xin,   // [M][N][FIN]
    const float* __restrict__ adj,   // [M][N][N]
    const float* __restrict__ W,     // [FIN][64]
    const float* __restrict__ a,     // [128]
    const float* __restrict__ gamma_, const float* __restrict__ beta_,
    float* __restrict__ gout)        // [M][N][64]
{
    __shared__ __align__(16) float h_lds[256 * 64];
    __shared__ __align__(16) float attq[4 * 256 * 4];   // per-wave private
    __shared__ float s1[256], s2[256];

    const int m = blockIdx.x;
    const int t = threadIdx.x;
    const int c = t & 63;
    const int w = t >> 6;

    float wreg[FIN];
#pragma unroll
    for (int f = 0; f < FIN; ++f) wreg[f] = W[f * 64 + c];

    const float* xg_ = xin + (size_t)m * NN * FIN;
    for (int i0 = 0; i0 < 64; ++i0) {
        int i = (i0 << 2) | w;
        float acc = 0.0f;
#pragma unroll
        for (int f4 = 0; f4 < FIN / 4; ++f4) {
            float4 xv = *(const float4*)&xg_[i * FIN + f4 * 4];
            acc += xv.x * wreg[f4*4] + xv.y * wreg[f4*4+1]
                 + xv.z * wreg[f4*4+2] + xv.w * wreg[f4*4+3];
        }
        h_lds[i * 64 + c] = acc;
    }
    __syncthreads();

    const float a1 = a[c], a2 = a[64 + c];
    for (int k = 0; k < 64; ++k) {
        int i = w * 64 + k;
        float hv = h_lds[i * 64 + c];
        float v1 = wave_sum(hv * a1);
        float v2 = wave_sum(hv * a2);
        if (c == 0) { s1[i] = v1; s2[i] = v2; }
    }
    __syncthreads();

    const float* adjm = adj + (size_t)m * NN * NN;
    const float gam = gamma_[c], bet = beta_[c];
    for (int qq = 0; qq < 16; ++qq) {
        int q = w + (qq << 2);
        int i0 = q * 4;
#pragma unroll
        for (int r = 0; r < 4; ++r) {
            int i = i0 + r;
            float si = s1[i];
            float p[4];
            float maxe = -3.4e38f;
#pragma unroll
            for (int jg = 0; jg < 4; ++jg) {
                int j = jg * 64 + c;
                float e = si + s2[j];
                e = (e > 0.0f) ? e : 0.2f * e;
                float ad = adjm[(size_t)i * NN + j];
                e = (ad > 0.0f) ? e : -9e15f;
                p[jg] = e;
                maxe = fmaxf(maxe, e);
            }
            maxe = wave_max(maxe);
            float sum = 0.0f;
#pragma unroll
            for (int jg = 0; jg < 4; ++jg) { p[jg] = __expf(p[jg] - maxe); sum += p[jg]; }
            sum = wave_sum(sum);
            float rinv = 1.0f / sum;
#pragma unroll
            for (int jg = 0; jg < 4; ++jg)
                attq[w * 1024 + (jg * 64 + c) * 4 + r] = p[jg] * rinv;
        }

        float acc0 = 0, acc1 = 0, acc2 = 0, acc3 = 0;
        const float* aq = &attq[w * 1024];
#pragma unroll 8
        for (int j = 0; j < 256; ++j) {
            float hv = h_lds[j * 64 + c];
            float4 av = *(const float4*)&aq[j * 4];
            acc0 += av.x * hv; acc1 += av.y * hv;
            acc2 += av.z * hv; acc3 += av.w * hv;
        }
        float accs[4] = {acc0, acc1, acc2, acc3};
#pragma unroll
        for (int r = 0; r < 4; ++r) {
            float v = accs[r];
            float sm = wave_sum(v);
            float sq = wave_sum(v * v);
            float mu = sm * (1.0f / 64.0f);
            float var = sq * (1.0f / 64.0f) - mu * mu;
            float hn = (v - mu) * rsqrtf(var + 1e-5f) * gam + bet;
            float o = (hn > 0.0f) ? hn : (__expf(hn) - 1.0f);
            gout[((size_t)m * NN + i0 + r) * 64 + c] = o;
        }
    }
}

// ---------------------------------------------------------------------------
// residual + gate*g, reshaped to sequence layout [B*N][T][H]
// ---------------------------------------------------------------------------
__global__ __launch_bounds__(256) void combine_kernel(
    const float* __restrict__ x,      // [B*S*N][32]
    const float* __restrict__ g1,     // [B*S*N][64]
    const float* __restrict__ res_W,  // [32][64]
    const float* __restrict__ res_b,  // [64]
    const float* __restrict__ alpha_p,
    float* __restrict__ seqout)       // [B*N][T][64]
{
    int row = blockIdx.x * 4 + (threadIdx.x >> 6);
    int h = threadIdx.x & 63;
    int mg = row >> 8, n = row & 255;
    int b = mg >> 6, s = mg & 63;
    const float* xr = x + (size_t)row * 32;
    float acc = res_b[h];
#pragma unroll
    for (int f4 = 0; f4 < 8; ++f4) {
        float4 xv = *(const float4*)&xr[f4 * 4];
        acc += xv.x * res_W[(f4*4    ) * 64 + h] + xv.y * res_W[(f4*4 + 1) * 64 + h]
             + xv.z * res_W[(f4*4 + 2) * 64 + h] + xv.w * res_W[(f4*4 + 3) * 64 + h];
    }
    float alpha = fminf(fmaxf(alpha_p[0], 0.0f), 1.0f);
    acc += alpha * g1[(size_t)row * 64 + h];
    seqout[(((size_t)(b * NN + n)) * TT + s) * 64 + h] = acc;
}

// ---------------------------------------------------------------------------
// xg GEMM v2: C[65536 x 256] = A @ Wih[dir] + bias, per dir.
// Block tile 256 rows x 128 cols; thread tile 16x8 (128 acc VGPRs).
// a_s is K-MAJOR [k][256 rows] so per-k a-frag reads are contiguous b128
// (16-lane broadcast, ~free); staging pays 16 scalar ds_writes/thread/chunk.
// Per k per thread: 6 ds_read_b128 (96 B) for 128 FMA -> ~1.15x DS-bound.
// grid: (MROWS/256, 2, 2)  [row tile, col half, dir]
// ---------------------------------------------------------------------------
template<int K>
__global__ __launch_bounds__(256, 2) void xg_gemm_kernel(
    const float* __restrict__ A,     // [65536][K]
    const float* __restrict__ Wih,   // [2][K][256]
    const float* __restrict__ bih,   // [2][256]
    const float* __restrict__ bhh,   // [2][256]
    float* __restrict__ xg)          // [2][65536][256]
{
    constexpr int KC = 16;
    __shared__ __align__(16) float a_s[KC * 256];   // [k][row] 16 KB
    __shared__ __align__(16) float b_s[KC * 128];   // [k][col]  8 KB

    const int tid = threadIdx.x;
    const int m0  = blockIdx.x * 256;
    const int c0  = blockIdx.y * 128;
    const int dir = blockIdx.z;

    const int tx = tid & 15;        // cols: c0 + tx*8 .. +7
    const int ty = tid >> 4;        // rows: m0 + ty*16 .. +15

    float acc[16][8];
#pragma unroll
    for (int r = 0; r < 16; ++r)
#pragma unroll
        for (int c = 0; c < 8; ++c) acc[r][c] = 0.0f;

    const float* Bd = Wih + (size_t)dir * K * 256;

    for (int kc = 0; kc < K; kc += KC) {
        // stage A (transposed): 256 rows x 16 k. Coalesced global read:
        // idx -> row=idx>>2, k4=(idx&3)*4; scatter 4 b32 into a_s[k][row].
#pragma unroll
        for (int i = 0; i < 4; ++i) {
            int idx = tid + i * 256;
            int row = idx >> 2, k4 = (idx & 3) << 2;
            float4 v = *(const float4*)&A[(size_t)(m0 + row) * K + kc + k4];
            a_s[(k4 + 0) * 256 + row] = v.x;
            a_s[(k4 + 1) * 256 + row] = v.y;
            a_s[(k4 + 2) * 256 + row] = v.z;
            a_s[(k4 + 3) * 256 + row] = v.w;
        }
        // stage B: 16 k x 128 cols (512 float4, 2/thread), direct layout
#pragma unroll
        for (int i = 0; i < 2; ++i) {
            int idx = tid + i * 256;
            int kr = idx >> 5, c4 = (idx & 31) << 2;
            *(float4*)&b_s[kr * 128 + c4] =
                *(const float4*)&Bd[(size_t)(kc + kr) * 256 + c0 + c4];
        }
        __syncthreads();

#pragma unroll 4
        for (int k = 0; k < KC; ++k) {
            const float* ak = &a_s[k * 256 + ty * 16];
            float4 a0 = *(const float4*)&ak[0];
            float4 a1 = *(const float4*)&ak[4];
            float4 a2 = *(const float4*)&ak[8];
            float4 a3 = *(const float4*)&ak[12];
            float4 b0 = *(const float4*)&b_s[k * 128 + tx * 8];
            float4 b1 = *(const float4*)&b_s[k * 128 + tx * 8 + 4];
            float av[16] = {a0.x,a0.y,a0.z,a0.w, a1.x,a1.y,a1.z,a1.w,
                            a2.x,a2.y,a2.z,a2.w, a3.x,a3.y,a3.z,a3.w};
            float bv[8]  = {b0.x,b0.y,b0.z,b0.w, b1.x,b1.y,b1.z,b1.w};
#pragma unroll
            for (int r = 0; r < 16; ++r)
#pragma unroll
                for (int c = 0; c < 8; ++c)
                    acc[r][c] += av[r] * bv[c];
        }
        __syncthreads();
    }

    // bias + store
    float4 b1v = *(const float4*)&bih[dir * 256 + c0 + tx * 8];
    float4 b2v = *(const float4*)&bhh[dir * 256 + c0 + tx * 8];
    float4 b1w = *(const float4*)&bih[dir * 256 + c0 + tx * 8 + 4];
    float4 b2w = *(const float4*)&bhh[dir * 256 + c0 + tx * 8 + 4];
    float4 biasA = make_float4(b1v.x + b2v.x, b1v.y + b2v.y, b1v.z + b2v.z, b1v.w + b2v.w);
    float4 biasB = make_float4(b1w.x + b2w.x, b1w.y + b2w.y, b1w.z + b2w.z, b1w.w + b2w.w);
    float* out = xg + (size_t)dir * MROWS * 256;
#pragma unroll
    for (int r = 0; r < 16; ++r) {
        size_t o = (size_t)(m0 + ty * 16 + r) * 256 + c0 + tx * 8;
        float4 v0 = make_float4(acc[r][0] + biasA.x, acc[r][1] + biasA.y,
                                acc[r][2] + biasA.z, acc[r][3] + biasA.w);
        float4 v1 = make_float4(acc[r][4] + biasB.x, acc[r][5] + biasB.y,
                                acc[r][6] + biasB.z, acc[r][7] + biasB.w);
        *(float4*)&out[o]     = v0;
        *(float4*)&out[o + 4] = v1;
    }
}

// ---------------------------------------------------------------------------
// LSTM recurrence: one block per (seq,dir); thread = gate k; Whh col in VGPRs.
// xg is [2][NSEQ][T][256] in NATURAL t order; dir=1 reads reversed.
// Next-step xg prefetched into a register so the global-load latency overlaps
// the barrier/recurrence instead of serializing after it.
// ---------------------------------------------------------------------------
__global__ __launch_bounds__(256) void lstm_rec_kernel(
    const float* __restrict__ xg,    // [2][NSEQ][T][256]
    const float* __restrict__ Whh,   // [2][64][256]
    float* __restrict__ out,         // write_all: o1 [NSEQ][T][128]; else final [NSEQ][128]
    int write_all)
{
    int sd = blockIdx.x;
    int seq = sd >> 1, dir = sd & 1;
    int t = threadIdx.x;
    float whh[64];
#pragma unroll
    for (int j = 0; j < 64; ++j) whh[j] = Whh[((size_t)dir * 64 + j) * 256 + t];

    __shared__ __align__(16) float h_s[64];
    __shared__ float gbuf[256];
    if (t < 64) h_s[t] = 0.0f;
    float cst = 0.0f;
    const float* xgb = xg + ((size_t)dir * NSEQ + seq) * TT * 256;
    int trow0 = dir ? (TT - 1) : 0;
    float gpre = xgb[trow0 * 256 + t];
    __syncthreads();

    for (int step = 0; step < TT; ++step) {
        float g = gpre;
        // prefetch next step's xg before we stall on barriers
        if (step + 1 < TT) {
            int trow = dir ? (TT - 2 - step) : (step + 1);
            gpre = xgb[trow * 256 + t];
        }
#pragma unroll
        for (int j4 = 0; j4 < 16; ++j4) {
            float4 hv = *(const float4*)&h_s[j4 * 4];
            g += hv.x * whh[j4*4] + hv.y * whh[j4*4+1]
               + hv.z * whh[j4*4+2] + hv.w * whh[j4*4+3];
        }
        float act = (t < 128 || t >= 192) ? sigmoid_f(g) : tanh_f(g);
        gbuf[t] = act;
        __syncthreads();
        if (t < 64) {
            float iv = gbuf[t], fv = gbuf[64 + t], gv = gbuf[128 + t], ov = gbuf[192 + t];
            cst = fv * cst + iv * gv;
            float h = ov * tanh_f(cst);
            h_s[t] = h;
            if (write_all) {
                int t_out = dir ? (TT - 1 - step) : step;
                out[((size_t)seq * TT + t_out) * 128 + dir * 64 + t] = h;
            } else if (step == TT - 1) {
                out[(size_t)seq * 128 + dir * 64 + t] = h;
            }
        }
        __syncthreads();
    }
}

// ---------------------------------------------------------------------------
// final FC: pred[seq] = final[seq] . fc_W + fc_b
// ---------------------------------------------------------------------------
__global__ __launch_bounds__(256) void fc_kernel(
    const float* __restrict__ fin,   // [NSEQ][128]
    const float* __restrict__ fc_W,  // [128]
    const float* __restrict__ fc_b,  // [1]
    float* __restrict__ outp)        // [NSEQ]
{
    int s = blockIdx.x * 256 + threadIdx.x;
    const float* fr = fin + (size_t)s * 128;
    float acc = fc_b[0];
#pragma unroll
    for (int k4 = 0; k4 < 32; ++k4) {
        float4 fv = *(const float4*)&fr[k4 * 4];
        float4 wv2 = *(const float4*)&fc_W[k4 * 4];
        acc += fv.x * wv2.x + fv.y * wv2.y + fv.z * wv2.z + fv.w * wv2.w;
    }
    outp[s] = acc;
}

// ---------------------------------------------------------------------------
extern "C" void kernel_launch(void* const* d_in, const int* in_sizes, int n_in,
                              void* d_out, int out_size, void* d_ws, size_t ws_size,
                              hipStream_t stream) {
    const float* x       = (const float*)d_in[0];
    const float* adj     = (const float*)d_in[1];
    const float* gat0_W  = (const float*)d_in[2];
    const float* gat0_a  = (const float*)d_in[3];
    const float* gat0_g  = (const float*)d_in[4];
    const float* gat0_b  = (const float*)d_in[5];
    const float* gat1_W  = (const float*)d_in[6];
    const float* gat1_a  = (const float*)d_in[7];
    const float* gat1_g  = (const float*)d_in[8];
    const float* gat1_b  = (const float*)d_in[9];
    const float* res_W   = (const float*)d_in[10];
    const float* res_b   = (const float*)d_in[11];
    const float* alpha_g = (const float*)d_in[12];
    const float* l0_Wih  = (const float*)d_in[13];
    const float* l0_Whh  = (const float*)d_in[14];
    const float* l0_bih  = (const float*)d_in[15];
    const float* l0_bhh  = (const float*)d_in[16];
    const float* l1_Wih  = (const float*)d_in[17];
    const float* l1_Whh  = (const float*)d_in[18];
    const float* l1_bih  = (const float*)d_in[19];
    const float* l1_bhh  = (const float*)d_in[20];
    const float* fc_W    = (const float*)d_in[21];
    const float* fc_b    = (const float*)d_in[22];

    float* ws = (float*)d_ws;
    float* g0    = ws;                    // 4,194,304   [M][N][64]
    float* g1    = ws + 4194304;          // 4,194,304   [M][N][64]
    float* seq   = ws + 8388608;          // 4,194,304   [B*N][T][64]
    float* xg    = ws + 12582912;         // 33,554,432  [2][65536][256]
    float* fin   = ws + 46137344;         // 131,072     [NSEQ][128]
    float* o1    = ws;                    // reuse g0+g1 [NSEQ][T][128]

    gat_kernel<32><<<MM, 256, 0, stream>>>(x, adj, gat0_W, gat0_a, gat0_g, gat0_b, g0);
    gat_kernel<64><<<MM, 256, 0, stream>>>(g0, adj, gat1_W, gat1_a, gat1_g, gat1_b, g1);
    combine_kernel<<<(BB*SS*NN)/4, 256, 0, stream>>>(x, g1, res_W, res_b, alpha_g, seq);
    xg_gemm_kernel<64><<<dim3(MROWS/256, 2, 2), 256, 0, stream>>>(seq, l0_Wih, l0_bih, l0_bhh, xg);
    lstm_rec_kernel<<<2*NSEQ, 256, 0, stream>>>(xg, l0_Whh, o1, 1);
    xg_gemm_kernel<128><<<dim3(MROWS/256, 2, 2), 256, 0, stream>>>(o1, l1_Wih, l1_bih, l1_bhh, xg);
    lstm_rec_kernel<<<2*NSEQ, 256, 0, stream>>>(xg, l1_Whh, fin, 0);
    fc_kernel<<<NSEQ/256, 256, 0, stream>>>(fin, fc_W, fc_b, (float*)d_out);
}

// Round 4
// 722.621 us; speedup vs baseline: 1.7798x; 1.2382x over previous
//
#include <hip/hip_runtime.h>
#include <math.h>

// Problem constants
#define BB 4
#define SS 64
#define NN 256
#define FF 32
#define HH 64
#define MM (BB*SS)      // 256 graphs
#define NSEQ (BB*NN)    // 1024 sequences
#define TT SS           // 64 timesteps
#define MROWS (NSEQ*TT) // 65536 GEMM rows

__device__ __forceinline__ float sigmoid_f(float x) { return 1.0f / (1.0f + __expf(-x)); }
__device__ __forceinline__ float tanh_f(float x) {
    float t = __expf(-2.0f * fabsf(x));
    float r = (1.0f - t) / (1.0f + t);
    return copysignf(r, x);
}

// ---------------------------------------------------------------------------
// GAT layer v2: one block per graph (256 blocks, 256 threads).
// Aggregation as a register-tiled GEMM (8x8 per thread) with softmax FUSED
// into the k-chunk staging: p = exp(lrelu(s1_i+s2_j))*mask computed while
// staging adj chunks, stored transposed p_s[k][i] (pad 260), row-sums
// accumulated on the fly, normalization folded into the epilogue.
// No max-subtraction: e bounded ~±5, masked entries exact 0.
// LDS: h[256][68] 68KB + p_s 2x[32][260] 65KB + s1/s2/srow 3KB = 136KB.
// ---------------------------------------------------------------------------
template<int FIN>
__global__ __launch_bounds__(256) void gat_kernel(
    const float* __restrict__ xin,   // [M][N][FIN]
    const float* __restrict__ adj,   // [M][N][N]
    const float* __restrict__ W,     // [FIN][64]
    const float* __restrict__ a,     // [128]
    const float* __restrict__ gamma_, const float* __restrict__ beta_,
    float* __restrict__ gout)        // [M][N][64]
{
    constexpr int HP = 68;            // padded h row (bank spread + b128 align)
    constexpr int KC = 32;            // k-chunk
    constexpr int PP = 260;           // padded p row
    __shared__ __align__(16) float h_lds[256 * HP];
    __shared__ __align__(16) float p_s[2][KC * PP];
    __shared__ float s1[256], s2[256], srow[256];

    const int m = blockIdx.x;
    const int tid = threadIdx.x;
    const int c = tid & 63;
    const int w = tid >> 6;

    // ---- phase A: h = x @ W  (thread (w,c): rows i%4==w, col c) ----
    {
        float wreg[FIN];
#pragma unroll
        for (int f = 0; f < FIN; ++f) wreg[f] = W[f * 64 + c];
        const float* xm = xin + (size_t)m * NN * FIN;
        for (int i0 = 0; i0 < 64; ++i0) {
            int i = (i0 << 2) | w;
            float acc = 0.0f;
#pragma unroll
            for (int f4 = 0; f4 < FIN / 4; ++f4) {
                float4 xv = *(const float4*)&xm[i * FIN + f4 * 4];
                acc += xv.x * wreg[f4*4] + xv.y * wreg[f4*4+1]
                     + xv.z * wreg[f4*4+2] + xv.w * wreg[f4*4+3];
            }
            h_lds[i * HP + c] = acc;
        }
    }
    __syncthreads();

    // ---- phase A2: s1,s2 for row tid (b128 row reads, 8-way ok) ----
    {
        float acc1 = 0.0f, acc2 = 0.0f;
        const float* hr = &h_lds[tid * HP];
#pragma unroll
        for (int c4 = 0; c4 < 16; ++c4) {
            float4 hv  = *(const float4*)&hr[c4 * 4];
            float4 av1 = *(const float4*)&a[c4 * 4];
            float4 av2 = *(const float4*)&a[64 + c4 * 4];
            acc1 += hv.x * av1.x + hv.y * av1.y + hv.z * av1.z + hv.w * av1.w;
            acc2 += hv.x * av2.x + hv.y * av2.y + hv.z * av2.z + hv.w * av2.w;
        }
        s1[tid] = acc1; s2[tid] = acc2;
    }
    __syncthreads();

    // ---- fused softmax-staging + GEMM ----
    const float* adjr = adj + ((size_t)m * NN + tid) * NN;   // adj row `tid`
    const int ty = tid >> 3;          // 0..31 -> rows i0 = ty*8
    const int tx = tid & 7;           // 0..7  -> cols c0 = tx*8
    const float s1v = s1[tid];

    float4 areg[8];                   // next chunk's adj values (row tid)
    float srow_acc = 0.0f;
    float acc[8][8];
#pragma unroll
    for (int r = 0; r < 8; ++r)
#pragma unroll
        for (int q = 0; q < 8; ++q) acc[r][q] = 0.0f;

    auto load_chunk = [&](int ch) {
#pragma unroll
        for (int q = 0; q < 8; ++q)
            areg[q] = *(const float4*)&adjr[ch * KC + q * 4];
    };
    auto make_p = [&](int ch, int buf) {
        float s2r[KC];
#pragma unroll
        for (int q = 0; q < 8; ++q) {
            float4 sv = *(const float4*)&s2[ch * KC + q * 4];
            s2r[q*4+0] = sv.x; s2r[q*4+1] = sv.y; s2r[q*4+2] = sv.z; s2r[q*4+3] = sv.w;
        }
        const float* af = (const float*)areg;
#pragma unroll
        for (int kk = 0; kk < KC; ++kk) {
            float e = s1v + s2r[kk];
            e = (e > 0.0f) ? e : 0.2f * e;
            float p = (af[kk] > 0.0f) ? __expf(e) : 0.0f;
            srow_acc += p;
            p_s[buf][kk * PP + tid] = p;
        }
    };

    load_chunk(0);
    make_p(0, 0);
    __syncthreads();

    for (int ch = 0; ch < 8; ++ch) {
        if (ch < 7) load_chunk(ch + 1);          // vmem in flight over consume
        // consume chunk ch from p_s[ch&1]
        {
            const float* pb = p_s[ch & 1];
            const int jb = ch * KC;
#pragma unroll 4
            for (int kk = 0; kk < KC; ++kk) {
                const float* pk = &pb[kk * PP + ty * 8];
                float4 p0 = *(const float4*)pk;
                float4 p1 = *(const float4*)(pk + 4);
                const float* hk = &h_lds[(jb + kk) * HP + tx * 8];
                float4 h0 = *(const float4*)hk;
                float4 h1 = *(const float4*)(hk + 4);
                float pv[8] = {p0.x,p0.y,p0.z,p0.w, p1.x,p1.y,p1.z,p1.w};
                float hv[8] = {h0.x,h0.y,h0.z,h0.w, h1.x,h1.y,h1.z,h1.w};
#pragma unroll
                for (int r = 0; r < 8; ++r)
#pragma unroll
                    for (int q = 0; q < 8; ++q)
                        acc[r][q] += pv[r] * hv[q];
            }
        }
        if (ch < 7) make_p(ch + 1, (ch + 1) & 1);
        else        srow[tid] = srow_acc;
        __syncthreads();
    }

    // ---- epilogue: normalize, LN over H (8 tx lanes x 8 vals), ELU, store ----
    const int i0 = ty * 8;
    float4 sr0 = *(const float4*)&srow[i0];
    float4 sr1 = *(const float4*)&srow[i0 + 4];
    float rinv[8] = {1.0f/sr0.x, 1.0f/sr0.y, 1.0f/sr0.z, 1.0f/sr0.w,
                     1.0f/sr1.x, 1.0f/sr1.y, 1.0f/sr1.z, 1.0f/sr1.w};
    float4 gm0 = *(const float4*)&gamma_[tx * 8];
    float4 gm1 = *(const float4*)&gamma_[tx * 8 + 4];
    float4 bt0 = *(const float4*)&beta_[tx * 8];
    float4 bt1 = *(const float4*)&beta_[tx * 8 + 4];
    float gm[8] = {gm0.x,gm0.y,gm0.z,gm0.w, gm1.x,gm1.y,gm1.z,gm1.w};
    float bt[8] = {bt0.x,bt0.y,bt0.z,bt0.w, bt1.x,bt1.y,bt1.z,bt1.w};

#pragma unroll
    for (int r = 0; r < 8; ++r) {
        float v[8];
        float sm = 0.0f, sq = 0.0f;
#pragma unroll
        for (int q = 0; q < 8; ++q) {
            v[q] = acc[r][q] * rinv[r];
            sm += v[q]; sq += v[q] * v[q];
        }
#pragma unroll
        for (int off = 1; off < 8; off <<= 1) {
            sm += __shfl_xor(sm, off);
            sq += __shfl_xor(sq, off);
        }
        float mu  = sm * (1.0f / 64.0f);
        float var = sq * (1.0f / 64.0f) - mu * mu;
        float rs  = rsqrtf(var + 1e-5f);
        float o[8];
#pragma unroll
        for (int q = 0; q < 8; ++q) {
            float hn = (v[q] - mu) * rs * gm[q] + bt[q];
            o[q] = (hn > 0.0f) ? hn : (__expf(hn) - 1.0f);
        }
        float* gp = &gout[((size_t)m * NN + i0 + r) * 64 + tx * 8];
        *(float4*)gp       = make_float4(o[0], o[1], o[2], o[3]);
        *(float4*)(gp + 4) = make_float4(o[4], o[5], o[6], o[7]);
    }
}

// ---------------------------------------------------------------------------
// residual + gate*g, reshaped to sequence layout [B*N][T][H]
// ---------------------------------------------------------------------------
__global__ __launch_bounds__(256) void combine_kernel(
    const float* __restrict__ x,      // [B*S*N][32]
    const float* __restrict__ g1,     // [B*S*N][64]
    const float* __restrict__ res_W,  // [32][64]
    const float* __restrict__ res_b,  // [64]
    const float* __restrict__ alpha_p,
    float* __restrict__ seqout)       // [B*N][T][64]
{
    int row = blockIdx.x * 4 + (threadIdx.x >> 6);
    int h = threadIdx.x & 63;
    int mg = row >> 8, n = row & 255;
    int b = mg >> 6, s = mg & 63;
    const float* xr = x + (size_t)row * 32;
    float acc = res_b[h];
#pragma unroll
    for (int f4 = 0; f4 < 8; ++f4) {
        float4 xv = *(const float4*)&xr[f4 * 4];
        acc += xv.x * res_W[(f4*4    ) * 64 + h] + xv.y * res_W[(f4*4 + 1) * 64 + h]
             + xv.z * res_W[(f4*4 + 2) * 64 + h] + xv.w * res_W[(f4*4 + 3) * 64 + h];
    }
    float alpha = fminf(fmaxf(alpha_p[0], 0.0f), 1.0f);
    acc += alpha * g1[(size_t)row * 64 + h];
    seqout[(((size_t)(b * NN + n)) * TT + s) * 64 + h] = acc;
}

// ---------------------------------------------------------------------------
// xg GEMM: C[65536 x 256] = A @ Wih[dir] + bias, per dir.
// Block tile 256x128; thread tile 16x8; a_s K-MAJOR.
// grid: (MROWS/256, 2, 2)
// ---------------------------------------------------------------------------
template<int K>
__global__ __launch_bounds__(256, 2) void xg_gemm_kernel(
    const float* __restrict__ A,     // [65536][K]
    const float* __restrict__ Wih,   // [2][K][256]
    const float* __restrict__ bih,   // [2][256]
    const float* __restrict__ bhh,   // [2][256]
    float* __restrict__ xg)          // [2][65536][256]
{
    constexpr int KC = 16;
    __shared__ __align__(16) float a_s[KC * 256];   // [k][row]
    __shared__ __align__(16) float b_s[KC * 128];   // [k][col]

    const int tid = threadIdx.x;
    const int m0  = blockIdx.x * 256;
    const int c0  = blockIdx.y * 128;
    const int dir = blockIdx.z;

    const int tx = tid & 15;
    const int ty = tid >> 4;

    float acc[16][8];
#pragma unroll
    for (int r = 0; r < 16; ++r)
#pragma unroll
        for (int c = 0; c < 8; ++c) acc[r][c] = 0.0f;

    const float* Bd = Wih + (size_t)dir * K * 256;

    for (int kc = 0; kc < K; kc += KC) {
#pragma unroll
        for (int i = 0; i < 4; ++i) {
            int idx = tid + i * 256;
            int row = idx >> 2, k4 = (idx & 3) << 2;
            float4 v = *(const float4*)&A[(size_t)(m0 + row) * K + kc + k4];
            a_s[(k4 + 0) * 256 + row] = v.x;
            a_s[(k4 + 1) * 256 + row] = v.y;
            a_s[(k4 + 2) * 256 + row] = v.z;
            a_s[(k4 + 3) * 256 + row] = v.w;
        }
#pragma unroll
        for (int i = 0; i < 2; ++i) {
            int idx = tid + i * 256;
            int kr = idx >> 5, c4 = (idx & 31) << 2;
            *(float4*)&b_s[kr * 128 + c4] =
                *(const float4*)&Bd[(size_t)(kc + kr) * 256 + c0 + c4];
        }
        __syncthreads();

#pragma unroll 4
        for (int k = 0; k < KC; ++k) {
            const float* ak = &a_s[k * 256 + ty * 16];
            float4 a0 = *(const float4*)&ak[0];
            float4 a1 = *(const float4*)&ak[4];
            float4 a2 = *(const float4*)&ak[8];
            float4 a3 = *(const float4*)&ak[12];
            float4 b0 = *(const float4*)&b_s[k * 128 + tx * 8];
            float4 b1 = *(const float4*)&b_s[k * 128 + tx * 8 + 4];
            float av[16] = {a0.x,a0.y,a0.z,a0.w, a1.x,a1.y,a1.z,a1.w,
                            a2.x,a2.y,a2.z,a2.w, a3.x,a3.y,a3.z,a3.w};
            float bv[8]  = {b0.x,b0.y,b0.z,b0.w, b1.x,b1.y,b1.z,b1.w};
#pragma unroll
            for (int r = 0; r < 16; ++r)
#pragma unroll
                for (int c = 0; c < 8; ++c)
                    acc[r][c] += av[r] * bv[c];
        }
        __syncthreads();
    }

    float4 b1v = *(const float4*)&bih[dir * 256 + c0 + tx * 8];
    float4 b2v = *(const float4*)&bhh[dir * 256 + c0 + tx * 8];
    float4 b1w = *(const float4*)&bih[dir * 256 + c0 + tx * 8 + 4];
    float4 b2w = *(const float4*)&bhh[dir * 256 + c0 + tx * 8 + 4];
    float4 biasA = make_float4(b1v.x + b2v.x, b1v.y + b2v.y, b1v.z + b2v.z, b1v.w + b2v.w);
    float4 biasB = make_float4(b1w.x + b2w.x, b1w.y + b2w.y, b1w.z + b2w.z, b1w.w + b2w.w);
    float* out = xg + (size_t)dir * MROWS * 256;
#pragma unroll
    for (int r = 0; r < 16; ++r) {
        size_t o = (size_t)(m0 + ty * 16 + r) * 256 + c0 + tx * 8;
        float4 v0 = make_float4(acc[r][0] + biasA.x, acc[r][1] + biasA.y,
                                acc[r][2] + biasA.z, acc[r][3] + biasA.w);
        float4 v1 = make_float4(acc[r][4] + biasB.x, acc[r][5] + biasB.y,
                                acc[r][6] + biasB.z, acc[r][7] + biasB.w);
        *(float4*)&out[o]     = v0;
        *(float4*)&out[o + 4] = v1;
    }
}

// ---------------------------------------------------------------------------
// LSTM recurrence: one block per (seq,dir); thread = gate k; Whh col in VGPRs.
// xg natural t order; dir=1 reads reversed; next-step xg prefetched.
// ---------------------------------------------------------------------------
__global__ __launch_bounds__(256) void lstm_rec_kernel(
    const float* __restrict__ xg,    // [2][NSEQ][T][256]
    const float* __restrict__ Whh,   // [2][64][256]
    float* __restrict__ out,
    int write_all)
{
    int sd = blockIdx.x;
    int seq = sd >> 1, dir = sd & 1;
    int t = threadIdx.x;
    float whh[64];
#pragma unroll
    for (int j = 0; j < 64; ++j) whh[j] = Whh[((size_t)dir * 64 + j) * 256 + t];

    __shared__ __align__(16) float h_s[64];
    __shared__ float gbuf[256];
    if (t < 64) h_s[t] = 0.0f;
    float cst = 0.0f;
    const float* xgb = xg + ((size_t)dir * NSEQ + seq) * TT * 256;
    int trow0 = dir ? (TT - 1) : 0;
    float gpre = xgb[trow0 * 256 + t];
    __syncthreads();

    for (int step = 0; step < TT; ++step) {
        float g = gpre;
        if (step + 1 < TT) {
            int trow = dir ? (TT - 2 - step) : (step + 1);
            gpre = xgb[trow * 256 + t];
        }
#pragma unroll
        for (int j4 = 0; j4 < 16; ++j4) {
            float4 hv = *(const float4*)&h_s[j4 * 4];
            g += hv.x * whh[j4*4] + hv.y * whh[j4*4+1]
               + hv.z * whh[j4*4+2] + hv.w * whh[j4*4+3];
        }
        float act = (t < 128 || t >= 192) ? sigmoid_f(g) : tanh_f(g);
        gbuf[t] = act;
        __syncthreads();
        if (t < 64) {
            float iv = gbuf[t], fv = gbuf[64 + t], gv = gbuf[128 + t], ov = gbuf[192 + t];
            cst = fv * cst + iv * gv;
            float h = ov * tanh_f(cst);
            h_s[t] = h;
            if (write_all) {
                int t_out = dir ? (TT - 1 - step) : step;
                out[((size_t)seq * TT + t_out) * 128 + dir * 64 + t] = h;
            } else if (step == TT - 1) {
                out[(size_t)seq * 128 + dir * 64 + t] = h;
            }
        }
        __syncthreads();
    }
}

// ---------------------------------------------------------------------------
__global__ __launch_bounds__(256) void fc_kernel(
    const float* __restrict__ fin,   // [NSEQ][128]
    const float* __restrict__ fc_W,  // [128]
    const float* __restrict__ fc_b,  // [1]
    float* __restrict__ outp)        // [NSEQ]
{
    int s = blockIdx.x * 256 + threadIdx.x;
    const float* fr = fin + (size_t)s * 128;
    float acc = fc_b[0];
#pragma unroll
    for (int k4 = 0; k4 < 32; ++k4) {
        float4 fv = *(const float4*)&fr[k4 * 4];
        float4 wv2 = *(const float4*)&fc_W[k4 * 4];
        acc += fv.x * wv2.x + fv.y * wv2.y + fv.z * wv2.z + fv.w * wv2.w;
    }
    outp[s] = acc;
}

// ---------------------------------------------------------------------------
extern "C" void kernel_launch(void* const* d_in, const int* in_sizes, int n_in,
                              void* d_out, int out_size, void* d_ws, size_t ws_size,
                              hipStream_t stream) {
    const float* x       = (const float*)d_in[0];
    const float* adj     = (const float*)d_in[1];
    const float* gat0_W  = (const float*)d_in[2];
    const float* gat0_a  = (const float*)d_in[3];
    const float* gat0_g  = (const float*)d_in[4];
    const float* gat0_b  = (const float*)d_in[5];
    const float* gat1_W  = (const float*)d_in[6];
    const float* gat1_a  = (const float*)d_in[7];
    const float* gat1_g  = (const float*)d_in[8];
    const float* gat1_b  = (const float*)d_in[9];
    const float* res_W   = (const float*)d_in[10];
    const float* res_b   = (const float*)d_in[11];
    const float* alpha_g = (const float*)d_in[12];
    const float* l0_Wih  = (const float*)d_in[13];
    const float* l0_Whh  = (const float*)d_in[14];
    const float* l0_bih  = (const float*)d_in[15];
    const float* l0_bhh  = (const float*)d_in[16];
    const float* l1_Wih  = (const float*)d_in[17];
    const float* l1_Whh  = (const float*)d_in[18];
    const float* l1_bih  = (const float*)d_in[19];
    const float* l1_bhh  = (const float*)d_in[20];
    const float* fc_W    = (const float*)d_in[21];
    const float* fc_b    = (const float*)d_in[22];

    float* ws = (float*)d_ws;
    float* g0    = ws;                    // [M][N][64]
    float* g1    = ws + 4194304;          // [M][N][64]
    float* seq   = ws + 8388608;          // [B*N][T][64]
    float* xg    = ws + 12582912;         // [2][65536][256]
    float* fin   = ws + 46137344;         // [NSEQ][128]
    float* o1    = ws;                    // reuse g0+g1 [NSEQ][T][128]

    gat_kernel<32><<<MM, 256, 0, stream>>>(x, adj, gat0_W, gat0_a, gat0_g, gat0_b, g0);
    gat_kernel<64><<<MM, 256, 0, stream>>>(g0, adj, gat1_W, gat1_a, gat1_g, gat1_b, g1);
    combine_kernel<<<(BB*SS*NN)/4, 256, 0, stream>>>(x, g1, res_W, res_b, alpha_g, seq);
    xg_gemm_kernel<64><<<dim3(MROWS/256, 2, 2), 256, 0, stream>>>(seq, l0_Wih, l0_bih, l0_bhh, xg);
    lstm_rec_kernel<<<2*NSEQ, 256, 0, stream>>>(xg, l0_Whh, o1, 1);
    xg_gemm_kernel<128><<<dim3(MROWS/256, 2, 2), 256, 0, stream>>>(o1, l1_Wih, l1_bih, l1_bhh, xg);
    lstm_rec_kernel<<<2*NSEQ, 256, 0, stream>>>(xg, l1_Whh, fin, 0);
    fc_kernel<<<NSEQ/256, 256, 0, stream>>>(fin, fc_W, fc_b, (float*)d_out);
}